// Round 4
// baseline (143.913 us; speedup 1.0000x reference)
//
#include <hip/hip_runtime.h>

#define VOCAB  100000
#define EMB    300
#define BATCH  16384
#define TOTAL  65536
#define NG     5
#define CHUNKS 75                  // EMB/4 float4 chunks per row (1200 B)

#define NBLK_A 4096                // 4 segments per block (4 waves)
#define NBLK_B 28800               // 98304 rows * 75 chunks / 256 threads
#define NBLK   (NBLK_A + NBLK_B)   // 32896
#define A_SPAN (NBLK_A * 8)        // A-blocks interleaved every 8th block

typedef float f4 __attribute__((ext_vector_type(4)));

// 64-ary cooperative lower_bound over sorted seg_ids[0..TOTAL):
// 3 dependent load+ballot rounds instead of ~17 serial binary-search steps.
__device__ __forceinline__ int lb64(const int* __restrict__ seg, int v, int lane) {
    int base = 0;
    unsigned long long m;
    // level 1: 64 chunks of 1024, probe each chunk's last element
    int p = lane * 1024 + 1023;
    m = __ballot(seg[p] < v);
    base += (int)__popcll(m) << 10;
    // level 2: 64 chunks of 16
    p = base + lane * 16 + 15;
    m = __ballot((p < TOTAL) && (seg[p] < v));
    base += (int)__popcll(m) << 4;
    // level 3: linear over the last 16
    p = base + lane;
    m = __ballot((lane < 16) && (p < TOTAL) && (seg[p] < v));
    base += (int)__popcll(m);
    return base;
}

__global__ __launch_bounds__(256) void fused_kernel(
    const float* __restrict__ W_in,
    const float* __restrict__ W_out,
    const int*   __restrict__ flat_idx,
    const int*   __restrict__ seg_ids,
    const int*   __restrict__ out_idx,
    const int*   __restrict__ ng_idx,
    float*       __restrict__ in_vec,
    float*       __restrict__ out_vec,
    float*       __restrict__ neg_vec)
{
    const unsigned bid = blockIdx.x;

    if (bid < A_SPAN && (bid & 7u) == 0u) {
        // ---------- A: fused gather + segment_sum, one wave per segment ----------
        const int aid  = (int)(bid >> 3);          // 0..NBLK_A-1
        const int wid  = threadIdx.x >> 6;
        const int lane = threadIdx.x & 63;
        const int seg  = aid * 4 + wid;

        const int start = lb64(seg_ids, seg,     lane);
        const int end   = lb64(seg_ids, seg + 1, lane);

        f4 acc0 = {0.f, 0.f, 0.f, 0.f};
        f4 acc1 = {0.f, 0.f, 0.f, 0.f};
        const bool extra = lane < (CHUNKS - 64);   // lanes 0..10 own chunk 64+lane

        for (int t0 = start; t0 < end; t0 += 64) {
            const int n = min(64, end - t0);
            // batch-load up to 64 token indices, broadcast via shfl
            const int myidx = (lane < n) ? flat_idx[t0 + lane] : 0;
            for (int j = 0; j < n; ++j) {
                const int idx = __shfl(myidx, j);
                const f4* row = reinterpret_cast<const f4*>(W_in + (size_t)idx * EMB);
                acc0 += row[lane];
                if (extra) acc1 += row[lane + 64];
            }
        }

        f4* dst = reinterpret_cast<f4*>(in_vec + (size_t)seg * EMB);
        dst[lane] = acc0;                          // empty segment -> zeros
        if (extra) dst[lane + 64] = acc1;
    } else {
        // ---------- B: plain row gathers (out_vec + neg_vec) ----------
        const int b = (bid < A_SPAN) ? (int)(bid - (bid >> 3) - 1u)
                                     : (int)(NBLK_A * 7 + (bid - A_SPAN));
        const int gid = b * 256 + (int)threadIdx.x;        // exactly 7,372,800 total
        const int row = gid / CHUNKS;
        const int c   = gid - row * CHUNKS;

        int idx;
        float* dstbase;
        if (row < BATCH) {
            idx = out_idx[row];
            dstbase = out_vec + (size_t)row * EMB;
        } else {
            const int rr = row - BATCH;
            idx = ng_idx[rr];
            dstbase = neg_vec + (size_t)rr * EMB;
        }

        const f4* src = reinterpret_cast<const f4*>(W_out + (size_t)idx * EMB);
        reinterpret_cast<f4*>(dstbase)[c] = src[c];
    }
}

extern "C" void kernel_launch(void* const* d_in, const int* in_sizes, int n_in,
                              void* d_out, int out_size, void* d_ws, size_t ws_size,
                              hipStream_t stream)
{
    const float* W_in   = (const float*)d_in[0];
    const float* W_out  = (const float*)d_in[1];
    const int*   flat   = (const int*)d_in[2];
    const int*   segids = (const int*)d_in[3];
    const int*   outidx = (const int*)d_in[4];
    const int*   ngidx  = (const int*)d_in[5];

    float* o       = (float*)d_out;
    float* in_vec  = o;                                  // [BATCH, EMB]
    float* out_vec = o + (size_t)BATCH * EMB;            // [BATCH, EMB]
    float* neg_vec = o + (size_t)2 * BATCH * EMB;        // [BATCH, NG, EMB]

    fused_kernel<<<NBLK, 256, 0, stream>>>(W_in, W_out, flat, segids,
                                           outidx, ngidx, in_vec, out_vec, neg_vec);
}

// Round 5
// 62.636 us; speedup vs baseline: 2.2976x; 2.2976x over previous
//
#include <hip/hip_runtime.h>

#define VOCAB  100000
#define EMB    300
#define BATCH  16384
#define TOTAL  65536
#define NG     5
#define CHUNKS 75                    // EMB/4 float4 chunks per row (1200 B)

#define ABLK     4096                // A: 4 segments per block (4 waves)
#define BTHREADS 3686400             // B threads (each does 2 chunks)
#define BBLK     (BTHREADS / 256)    // 14400
#define NBLK     (ABLK + BBLK)       // 18496

typedef float f4 __attribute__((ext_vector_type(4)));

// ---------------- Kernel P: segment boundary table ----------------
// ptr[b] = lower_bound(seg_ids, b) for b in [0, BATCH]; one coalesced sweep.
// Each b is written by exactly one thread (ranges (seg[t-1], seg[t]] are
// disjoint since seg_ids is sorted), so no init/atomics needed.
__global__ __launch_bounds__(256) void bounds_kernel(
    const int* __restrict__ seg_ids,
    int*       __restrict__ ptr)
{
    const int t   = blockIdx.x * 256 + threadIdx.x;      // 0..TOTAL-1
    const int cur = seg_ids[t];
    const int prev = (t == 0) ? -1 : seg_ids[t - 1];
    for (int b = prev + 1; b <= cur; ++b) ptr[b] = t;
    if (t == TOTAL - 1)
        for (int b = cur + 1; b <= BATCH; ++b) ptr[b] = TOTAL;
}

// ---------------- Fused kernel: A-blocks first, then B-blocks ----------------
__global__ __launch_bounds__(256) void fused2_kernel(
    const float* __restrict__ W_in,
    const float* __restrict__ W_out,
    const int*   __restrict__ flat_idx,
    const int*   __restrict__ ptr,
    const int*   __restrict__ out_idx,
    const int*   __restrict__ ng_idx,
    float*       __restrict__ in_vec,
    float*       __restrict__ out_vec,
    float*       __restrict__ neg_vec)
{
    const int bid = blockIdx.x;

    if (bid < ABLK) {
        // ---------- A: gather + segment_sum, one wave per segment ----------
        const int wid  = threadIdx.x >> 6;
        const int lane = threadIdx.x & 63;
        const int seg  = bid * 4 + wid;

        const int start = ptr[seg];
        const int end   = ptr[seg + 1];

        f4 acc0 = {0.f, 0.f, 0.f, 0.f};
        f4 acc1 = {0.f, 0.f, 0.f, 0.f};
        const bool extra = lane < (CHUNKS - 64);   // lanes 0..10 own chunk 64+lane

        for (int t0 = start; t0 < end; t0 += 64) {
            const int n = min(64, end - t0);
            // batch-load up to 64 token indices, broadcast via shfl
            const int myidx = (lane < n) ? flat_idx[t0 + lane] : 0;
            for (int j = 0; j < n; ++j) {
                const int idx = __shfl(myidx, j);
                const f4* row = reinterpret_cast<const f4*>(W_in + (size_t)idx * EMB);
                acc0 += row[lane];
                if (extra) acc1 += row[lane + 64];
            }
        }

        f4* dst = reinterpret_cast<f4*>(in_vec + (size_t)seg * EMB);
        dst[lane] = acc0;                          // empty segment -> zeros
        if (extra) dst[lane + 64] = acc1;
    } else {
        // ---------- B: plain row gathers, 2 independent chunks per thread ----------
        const int gid = (bid - ABLK) * 256 + (int)threadIdx.x;
#pragma unroll
        for (int k = 0; k < 2; ++k) {
            const int g   = gid + k * BTHREADS;    // < 7,372,800
            const int row = g / CHUNKS;
            const int c   = g - row * CHUNKS;

            int idx;
            float* dstbase;
            if (row < BATCH) {
                idx = out_idx[row];
                dstbase = out_vec + (size_t)row * EMB;
            } else {
                const int rr = row - BATCH;
                idx = ng_idx[rr];
                dstbase = neg_vec + (size_t)rr * EMB;
            }

            const f4* src = reinterpret_cast<const f4*>(W_out + (size_t)idx * EMB);
            reinterpret_cast<f4*>(dstbase)[c] = src[c];
        }
    }
}

extern "C" void kernel_launch(void* const* d_in, const int* in_sizes, int n_in,
                              void* d_out, int out_size, void* d_ws, size_t ws_size,
                              hipStream_t stream)
{
    const float* W_in   = (const float*)d_in[0];
    const float* W_out  = (const float*)d_in[1];
    const int*   flat   = (const int*)d_in[2];
    const int*   segids = (const int*)d_in[3];
    const int*   outidx = (const int*)d_in[4];
    const int*   ngidx  = (const int*)d_in[5];

    float* o       = (float*)d_out;
    float* in_vec  = o;                                  // [BATCH, EMB]
    float* out_vec = o + (size_t)BATCH * EMB;            // [BATCH, EMB]
    float* neg_vec = o + (size_t)2 * BATCH * EMB;        // [BATCH, NG, EMB]

    int* ptr = (int*)d_ws;                               // (BATCH+1) ints = 64 KiB + 4

    bounds_kernel<<<TOTAL / 256, 256, 0, stream>>>(segids, ptr);
    fused2_kernel<<<NBLK, 256, 0, stream>>>(W_in, W_out, flat, ptr,
                                            outidx, ngidx, in_vec, out_vec, neg_vec);
}

// Round 6
// 60.545 us; speedup vs baseline: 2.3770x; 1.0345x over previous
//
#include <hip/hip_runtime.h>

#define VOCAB  100000
#define EMB    300
#define BATCH  16384
#define TOTAL  65536
#define NG     5
#define CHUNKS 75                    // EMB/4 float4 chunks per row (1200 B)

#define ABLK     4096                // A: 4 segments per block (4 waves)
#define BTHREADS 3686400             // B threads (each does 2 chunks)
#define BBLK     (BTHREADS / 256)    // 14400
#define NBLK     (ABLK + BBLK)       // 18496

typedef float f4 __attribute__((ext_vector_type(4)));

// ---------------- Kernel P: segment boundary table ----------------
// ptr[b] = lower_bound(seg_ids, b) for b in [0, BATCH]; one coalesced sweep.
__global__ __launch_bounds__(256) void bounds_kernel(
    const int* __restrict__ seg_ids,
    int*       __restrict__ ptr)
{
    const int t   = blockIdx.x * 256 + threadIdx.x;      // 0..TOTAL-1
    const int cur = seg_ids[t];
    const int prev = (t == 0) ? -1 : seg_ids[t - 1];
    for (int b = prev + 1; b <= cur; ++b) ptr[b] = t;
    if (t == TOTAL - 1)
        for (int b = cur + 1; b <= BATCH; ++b) ptr[b] = TOTAL;
}

// ---------------- Fused kernel: A-blocks first, then B-blocks ----------------
// Output stores are NON-TEMPORAL: the 137 MB write stream must not evict the
// 240 MB of embedding tables from L3 (tables + outputs = 378 MB > 256 MB L3).
__global__ __launch_bounds__(256) void fused2_kernel(
    const float* __restrict__ W_in,
    const float* __restrict__ W_out,
    const int*   __restrict__ flat_idx,
    const int*   __restrict__ ptr,
    const int*   __restrict__ out_idx,
    const int*   __restrict__ ng_idx,
    float*       __restrict__ in_vec,
    float*       __restrict__ out_vec,
    float*       __restrict__ neg_vec)
{
    const int bid = blockIdx.x;

    if (bid < ABLK) {
        // ---------- A: gather + segment_sum, one wave per segment ----------
        const int wid  = threadIdx.x >> 6;
        const int lane = threadIdx.x & 63;
        const int seg  = bid * 4 + wid;

        const int start = ptr[seg];
        const int end   = ptr[seg + 1];

        f4 acc0 = {0.f, 0.f, 0.f, 0.f};
        f4 acc1 = {0.f, 0.f, 0.f, 0.f};
        const bool extra = lane < (CHUNKS - 64);   // lanes 0..10 own chunk 64+lane

        for (int t0 = start; t0 < end; t0 += 64) {
            const int n = min(64, end - t0);
            // batch-load up to 64 token indices, broadcast via shfl
            const int myidx = (lane < n) ? flat_idx[t0 + lane] : 0;
            for (int j = 0; j < n; ++j) {
                const int idx = __shfl(myidx, j);
                const f4* row = reinterpret_cast<const f4*>(W_in + (size_t)idx * EMB);
                acc0 += row[lane];
                if (extra) acc1 += row[lane + 64];
            }
        }

        f4* dst = reinterpret_cast<f4*>(in_vec + (size_t)seg * EMB);
        __builtin_nontemporal_store(acc0, dst + lane);       // empty segment -> zeros
        if (extra) __builtin_nontemporal_store(acc1, dst + lane + 64);
    } else {
        // ---------- B: plain row gathers, 2 independent chunks per thread ----------
        const int gid = (bid - ABLK) * 256 + (int)threadIdx.x;
#pragma unroll
        for (int k = 0; k < 2; ++k) {
            const int g   = gid + k * BTHREADS;    // < 7,372,800
            const int row = g / CHUNKS;
            const int c   = g - row * CHUNKS;

            int idx;
            float* dstbase;
            if (row < BATCH) {
                idx = out_idx[row];
                dstbase = out_vec + (size_t)row * EMB;
            } else {
                const int rr = row - BATCH;
                idx = ng_idx[rr];
                dstbase = neg_vec + (size_t)rr * EMB;
            }

            const f4* src = reinterpret_cast<const f4*>(W_out + (size_t)idx * EMB);
            const f4 v = src[c];
            __builtin_nontemporal_store(v, reinterpret_cast<f4*>(dstbase) + c);
        }
    }
}

extern "C" void kernel_launch(void* const* d_in, const int* in_sizes, int n_in,
                              void* d_out, int out_size, void* d_ws, size_t ws_size,
                              hipStream_t stream)
{
    const float* W_in   = (const float*)d_in[0];
    const float* W_out  = (const float*)d_in[1];
    const int*   flat   = (const int*)d_in[2];
    const int*   segids = (const int*)d_in[3];
    const int*   outidx = (const int*)d_in[4];
    const int*   ngidx  = (const int*)d_in[5];

    float* o       = (float*)d_out;
    float* in_vec  = o;                                  // [BATCH, EMB]
    float* out_vec = o + (size_t)BATCH * EMB;            // [BATCH, EMB]
    float* neg_vec = o + (size_t)2 * BATCH * EMB;        // [BATCH, NG, EMB]

    int* ptr = (int*)d_ws;                               // (BATCH+1) ints = 64 KiB + 4

    bounds_kernel<<<TOTAL / 256, 256, 0, stream>>>(segids, ptr);
    fused2_kernel<<<NBLK, 256, 0, stream>>>(W_in, W_out, flat, ptr,
                                            outidx, ngidx, in_vec, out_vec, neg_vec);
}